// Round 9
// baseline (210.455 us; speedup 1.0000x reference)
//
#include <hip/hip_runtime.h>
#include <hip/hip_bf16.h>

// out[512, 65536] = inputs[512,256] @ features[65536,256]^T  (fp32 in/out)
//
// v10: barrier-free main loop with A ENTIRELY IN REGISTERS.
// v9's post-mortem: each per-step __syncthreads drains vmcnt(0), which
// includes the C stores (~200-500cy ack) -> 32 drains ~= the 7-9us gap to
// the traffic floor. Fix: remove every sync point after Bs staging.
//   - Bs [128][256] bf16 staged once (64 KB, v3-proven XOR swizzle,
//     conflict-free ds_read_b128), read-only after ONE __syncthreads.
//   - A per wave per mp = 64 rows x 256 k = 32 bf16x8 frags = 128 VGPR,
//     loaded from the L2-resident bf16 ws at mp START (32 independent
//     loads, latency hidden under kb0's ds_reads + the 8-step MFMA run).
//   - 4 m-passes, free-running waves: A-load and store bursts stagger
//     across waves/blocks -> smooth HBM streams. No DMA, no barriers.
//   - Traffic: B 64 MB once + C 134 MB + A ~0 (L2)  ->  ~29-31 us floor.

#define M_DIM 512
#define N_DIM 65536
#define K_DIM 256
#define BN 128

typedef __bf16 bf16x8 __attribute__((ext_vector_type(8)));
typedef float f32x4 __attribute__((ext_vector_type(4)));

// ---- kernel 1: inputs [512][256] fp32 -> bf16 ws, row-major ----
__global__ __launch_bounds__(256) void cvt_inputs(const float* __restrict__ A,
                                                  __bf16* __restrict__ Aw) {
    const int t = blockIdx.x * 256 + threadIdx.x;   // 16384 threads x 8 elems
    const float* src = A + (size_t)t * 8;
    f32x4 v0 = *(const f32x4*)src;
    f32x4 v1 = *(const f32x4*)(src + 4);
    bf16x8 h;
    h[0] = (__bf16)v0[0]; h[1] = (__bf16)v0[1];
    h[2] = (__bf16)v0[2]; h[3] = (__bf16)v0[3];
    h[4] = (__bf16)v1[0]; h[5] = (__bf16)v1[1];
    h[6] = (__bf16)v1[2]; h[7] = (__bf16)v1[3];
    *(bf16x8*)(Aw + (size_t)t * 8) = h;
}

__global__ __launch_bounds__(256, 2) void hm_gemm_bt(
    const __bf16* __restrict__ Aw,  // [512][256] bf16 ws (L2-resident)
    const float*  __restrict__ B,   // features [65536][256] fp32
    float* __restrict__ C)          // out [512][65536] fp32
{
    __shared__ __align__(16) __bf16 Bs[BN * K_DIM];  // 64 KB, full-K B panel

    const int tid  = threadIdx.x;
    const int lane = tid & 63;
    const int wave = tid >> 6;            // 4 waves, 2x2 grid of 64x64 subtiles
    const int wm   = (wave >> 1) * 64;
    const int wn   = (wave & 1) * 64;
    const int n0   = blockIdx.x * BN;     // grid = 512, all co-resident

    const int lrow = lane & 15;
    const int lh   = lane >> 4;           // 0..3: k-slot / n-reg group
    const int lx   = lane & 7;            // Bs XOR key (row&7 == lane&7)

    // ---- stage full-K B panel once: 128 rows x 256 k, fp32 -> bf16, XOR-swz
    #pragma unroll 4
    for (int it = 0; it < 16; ++it) {
        const int cc  = it * 256 + tid;   // 0..4095 bf16x8 slots
        const int row = cc >> 5;
        const int s   = cc & 31;
        const float* src = B + (size_t)(n0 + row) * K_DIM + s * 8;
        f32x4 v0 = *(const f32x4*)(src);
        f32x4 v1 = *(const f32x4*)(src + 4);
        bf16x8 h;
        h[0] = (__bf16)v0[0]; h[1] = (__bf16)v0[1];
        h[2] = (__bf16)v0[2]; h[3] = (__bf16)v0[3];
        h[4] = (__bf16)v1[0]; h[5] = (__bf16)v1[1];
        h[6] = (__bf16)v1[2]; h[7] = (__bf16)v1[3];
        const int sst = s ^ (row & 7);
        *(bf16x8*)&Bs[row * K_DIM + sst * 8] = h;
    }
    __syncthreads();   // ONLY barrier in the kernel; Bs read-only after

    for (int mp = 0; mp < 4; ++mp) {
        // ---- load this mp's entire A operand into registers:
        // af[q], q = kb*4 + i  ->  row = mp*128 + wm + i*16 + lrow,
        //                          k   = kb*32 + lh*8   (16 B per frag)
        const __bf16* Ab = Aw + (size_t)(mp * 128 + wm + lrow) * K_DIM + lh * 8;
        bf16x8 af[32];
        #pragma unroll
        for (int q = 0; q < 32; ++q)   // kb-major: first-needed frags first
            af[q] = *(const bf16x8*)(Ab + (size_t)(q & 3) * (16 * K_DIM)
                                        + (q >> 2) * 32);

        f32x4 acc[4][4];
        #pragma unroll
        for (int i = 0; i < 4; ++i)
            #pragma unroll
            for (int j = 0; j < 4; ++j)
                acc[i][j] = f32x4{0.f, 0.f, 0.f, 0.f};

        #pragma unroll
        for (int kb = 0; kb < 8; ++kb) {
            bf16x8 bfr[4];
            #pragma unroll
            for (int j = 0; j < 4; ++j) {
                const int row = wn + j * 16 + lrow;
                const int pos = (kb * 4 + lh) ^ lx;
                bfr[j] = *(const bf16x8*)&Bs[row * K_DIM + pos * 8];
            }
            #pragma unroll
            for (int i = 0; i < 4; ++i)
                #pragma unroll
                for (int j = 0; j < 4; ++j)
                    acc[i][j] = __builtin_amdgcn_mfma_f32_16x16x32_bf16(
                        bfr[j], af[kb * 4 + i], acc[i][j], 0, 0, 0); // D.row->n
        }

        // ---- stores: lane holds C[m = ..+lrow][n = ..+j*16+lh*4+0..3]
        #pragma unroll
        for (int i = 0; i < 4; ++i) {
            const size_t rowb = (size_t)(mp * 128 + wm + i * 16 + lrow) * N_DIM;
            #pragma unroll
            for (int j = 0; j < 4; ++j)
                *(f32x4*)(C + rowb + (n0 + wn + j * 16 + lh * 4)) = acc[i][j];
        }
    }
}

extern "C" void kernel_launch(void* const* d_in, const int* in_sizes, int n_in,
                              void* d_out, int out_size, void* d_ws, size_t ws_size,
                              hipStream_t stream) {
    // setup_inputs order: inputs, indexes, features, mIoU, IoU
    const float* inputs   = (const float*)d_in[0];
    const float* features = (const float*)d_in[2];
    float* out = (float*)d_out;
    __bf16* Aw = (__bf16*)d_ws;          // 256 KB of workspace

    hipLaunchKernelGGL(cvt_inputs, dim3(M_DIM * K_DIM / (256 * 8)), dim3(256),
                       0, stream, inputs, Aw);

    hipLaunchKernelGGL(hm_gemm_bt, dim3(N_DIM / BN), dim3(256), 0, stream,
                       Aw, features, out);
}

// Round 10
// 195.668 us; speedup vs baseline: 1.0756x; 1.0756x over previous
//
#include <hip/hip_runtime.h>
#include <hip/hip_bf16.h>

// out[512, 65536] = inputs[512,256] @ features[65536,256]^T  (fp32 in/out)
//
// v11 = v9 (best verified: 197.2us total, GEMM ~38us) with the per-step
// vmcnt(0) drain replaced by a COUNTED drain:
//   step t (wave-local program order, pinned by sched_barrier(0)):
//     {2x gload_lds (As tile t+1)} | ds_reads + 16 MFMA | {2x C stores}
//     sched_barrier ; s_waitcnt vmcnt(2 if stores else 0) ; sched_barrier ;
//     s_barrier
//   vmcnt(2) leaves only THIS step's 2 stores outstanding: each wave's own
//   DMAs are landed before s_barrier -> collectively all 8 chunks landed
//   (same guarantee __syncthreads gave, minus the fresh-store ack wait).
//   C stores are never read by any wave -> safe in flight.
// Everything else identical to v9: BN=128, BK=32 As[2] double-buffer DMA,
// Bs full-K XOR-swizzled panel staged once, store-interleave via accs.

#define M_DIM 512
#define N_DIM 65536
#define K_DIM 256
#define BN 128
#define BK 32

typedef __bf16 bf16x8 __attribute__((ext_vector_type(8)));
typedef float f32x4 __attribute__((ext_vector_type(4)));

// ---- kernel 1: inputs [512][256] fp32 -> bf16 ws, row-major ----
__global__ __launch_bounds__(256) void cvt_inputs(const float* __restrict__ A,
                                                  __bf16* __restrict__ Aw) {
    const int t = blockIdx.x * 256 + threadIdx.x;   // 16384 threads x 8 elems
    const float* src = A + (size_t)t * 8;
    f32x4 v0 = *(const f32x4*)src;
    f32x4 v1 = *(const f32x4*)(src + 4);
    bf16x8 h;
    h[0] = (__bf16)v0[0]; h[1] = (__bf16)v0[1];
    h[2] = (__bf16)v0[2]; h[3] = (__bf16)v0[3];
    h[4] = (__bf16)v1[0]; h[5] = (__bf16)v1[1];
    h[6] = (__bf16)v1[2]; h[7] = (__bf16)v1[3];
    *(bf16x8*)(Aw + (size_t)t * 8) = h;
}

static __device__ __forceinline__ void gload_lds16(const __bf16* g, __bf16* l) {
    __builtin_amdgcn_global_load_lds(
        (const __attribute__((address_space(1))) void*)g,
        (__attribute__((address_space(3))) void*)l, 16, 0, 0);
}

__global__ __launch_bounds__(256, 2) void hm_gemm_bt(
    const __bf16* __restrict__ Aw,  // [512][256] bf16 ws
    const float*  __restrict__ B,   // features [65536][256] fp32
    float* __restrict__ C)          // out [512][65536] fp32
{
    __shared__ __align__(16) __bf16 Bs[BN * K_DIM];   // 64 KB, full-K B panel
    __shared__ __align__(16) __bf16 As[2][128 * BK];  // 2 x 8 KB, linear

    const int tid  = threadIdx.x;
    const int lane = tid & 63;
    const int wave = tid >> 6;            // 4 waves, 2x2 grid of 64x64 subtiles
    const int wm   = (wave >> 1) * 64;
    const int wn   = (wave & 1) * 64;
    const int n0   = blockIdx.x * BN;     // grid = 512, all co-resident

    const int lrow = lane & 15;
    const int lx   = lane & 7;            // Bs XOR key (row&7 == lane&7)

    // A-DMA lane geometry: chunk c (1 KB): lane l writes LDS elems c*512+l*8
    // -> row_local = c*16 + (l>>2), k-elems (l&3)*8. Linear both sides.
    const int ar = lane >> 2;
    const int ak = (lane & 3) * 8;

    // ---- issue step-0 A tile DMA first: flies during Bs staging
    #pragma unroll
    for (int q = 0; q < 2; ++q) {
        const int c = wave * 2 + q;
        gload_lds16(Aw + (size_t)(c * 16 + ar) * K_DIM + ak, &As[0][c * 512]);
    }

    // ---- stage full-K B panel once: 128 rows x 256 k, fp32 -> bf16, XOR-swz
    #pragma unroll 4
    for (int it = 0; it < 16; ++it) {
        const int cc  = it * 256 + tid;   // 0..4095 bf16x8 slots
        const int row = cc >> 5;
        const int s   = cc & 31;
        const float* src = B + (size_t)(n0 + row) * K_DIM + s * 8;
        f32x4 v0 = *(const f32x4*)(src);
        f32x4 v1 = *(const f32x4*)(src + 4);
        bf16x8 h;
        h[0] = (__bf16)v0[0]; h[1] = (__bf16)v0[1];
        h[2] = (__bf16)v0[2]; h[3] = (__bf16)v0[3];
        h[4] = (__bf16)v1[0]; h[5] = (__bf16)v1[1];
        h[6] = (__bf16)v1[2]; h[7] = (__bf16)v1[3];
        const int sst = s ^ (row & 7);
        *(bf16x8*)&Bs[row * K_DIM + sst * 8] = h;
    }
    __syncthreads();   // full drain: Bs AND step-0 A tile ready

    f32x4 acc[4][4], accs[4][4];

    // ---- 32 steps: t -> (mp = t>>3, kb = t&7). One (counted) barrier/step.
    #pragma unroll
    for (int t = 0; t < 32; ++t) {
        const int mp = t >> 3;
        const int kb = t & 7;

        // issue NEXT step's A-DMA into the other buffer (hidden under compute,
        // landed by this step's end barrier).
        if (t < 31) {
            const int tn  = t + 1;
            const int mpn = tn >> 3;
            const int kbn = tn & 7;
            #pragma unroll
            for (int q = 0; q < 2; ++q) {
                const int c = wave * 2 + q;
                gload_lds16(Aw + (size_t)(mpn * 128 + c * 16 + ar) * K_DIM
                               + kbn * BK + ak,
                            &As[tn & 1][c * 512]);
            }
        }
        // pin: DMAs stay the OLDEST vmem ops of this step (stores can't hoist
        // above them) -> vmcnt(2) below provably covers both DMAs.
        __builtin_amdgcn_sched_barrier(0);

        if (kb == 0) {
            #pragma unroll
            for (int i = 0; i < 4; ++i)
                #pragma unroll
                for (int j = 0; j < 4; ++j)
                    acc[i][j] = f32x4{0.f, 0.f, 0.f, 0.f};
        }

        bf16x8 af[4], bfr[4];
        #pragma unroll
        for (int i = 0; i < 4; ++i)
            af[i] = *(const bf16x8*)
                &As[t & 1][(wm + i * 16 + lrow) * BK + (lane >> 4) * 8];
        #pragma unroll
        for (int j = 0; j < 4; ++j) {
            const int row = wn + j * 16 + lrow;
            const int pos = (kb * 4 + (lane >> 4)) ^ lx;
            bfr[j] = *(const bf16x8*)&Bs[row * K_DIM + pos * 8];
        }
        #pragma unroll
        for (int i = 0; i < 4; ++i)
            #pragma unroll
            for (int j = 0; j < 4; ++j)
                acc[i][j] = __builtin_amdgcn_mfma_f32_16x16x32_bf16(
                    bfr[j], af[i], acc[i][j], 0, 0, 0);   // swapped: D.row -> n

        // ---- interleaved C stores: 2 per step, previous mp's tile
        if (t >= 8) {
            const int pmp = mp - 1;
            #pragma unroll
            for (int q = 0; q < 2; ++q) {
                const int sidx = kb * 2 + q;          // 0..15 over the mp
                const int i = sidx >> 2;
                const int j = sidx & 3;
                const size_t rowb =
                    (size_t)(pmp * 128 + wm + i * 16 + lrow) * N_DIM;
                *(f32x4*)(C + rowb + (n0 + wn + j * 16 + (lane >> 4) * 4)) =
                    accs[i][j];
            }
        }

        // mp finished: shadow-copy acc so next mp's steps can store it
        if (kb == 7) {
            #pragma unroll
            for (int i = 0; i < 4; ++i)
                #pragma unroll
                for (int j = 0; j < 4; ++j)
                    accs[i][j] = acc[i][j];
        }

        // counted drain + raw barrier: wait own DMAs (and all older vmem),
        // leave only this step's 2 fresh C-stores in flight.
        if (t < 31) {
            __builtin_amdgcn_sched_barrier(0);
            if (t >= 8)
                asm volatile("s_waitcnt vmcnt(2)" ::: "memory");
            else
                asm volatile("s_waitcnt vmcnt(0)" ::: "memory");
            __builtin_amdgcn_sched_barrier(0);
            __builtin_amdgcn_s_barrier();
        }
    }

    // ---- final mp (mp=3) stores
    {
        const int ln = (lane >> 4) * 4;
        #pragma unroll
        for (int i = 0; i < 4; ++i) {
            const size_t rowb = (size_t)(3 * 128 + wm + i * 16 + lrow) * N_DIM;
            #pragma unroll
            for (int j = 0; j < 4; ++j)
                *(f32x4*)(C + rowb + (n0 + wn + j * 16 + ln)) = accs[i][j];
        }
    }
}

extern "C" void kernel_launch(void* const* d_in, const int* in_sizes, int n_in,
                              void* d_out, int out_size, void* d_ws, size_t ws_size,
                              hipStream_t stream) {
    // setup_inputs order: inputs, indexes, features, mIoU, IoU
    const float* inputs   = (const float*)d_in[0];
    const float* features = (const float*)d_in[2];
    float* out = (float*)d_out;
    __bf16* Aw = (__bf16*)d_ws;          // 256 KB of workspace

    hipLaunchKernelGGL(cvt_inputs, dim3(M_DIM * K_DIM / (256 * 8)), dim3(256),
                       0, stream, inputs, Aw);

    hipLaunchKernelGGL(hm_gemm_bt, dim3(N_DIM / BN), dim3(256), 0, stream,
                       Aw, features, out);
}